// Round 14
// baseline (199.554 us; speedup 1.0000x reference)
//
#include <hip/hip_runtime.h>

using int32x4 = __attribute__((ext_vector_type(4))) int;

#define BM 256
#define BN 128
#define BUFSZ 49152   // one K-tile buffer: A 32K (256r x 128B) + B 16K (128r x 128B)

// ---------------------------------------------------------------------------
// Kernel 1: pack int32 activations -> int8 (values in [-128,127])
// ---------------------------------------------------------------------------
__global__ __launch_bounds__(256) void pack_x_kernel(const int32x4* __restrict__ x,
                                                     int32x4* __restrict__ xp,
                                                     int nvec) {
    int t = blockIdx.x * 256 + threadIdx.x;
    if (t >= nvec) return;
    int32x4 a = x[t * 4 + 0];
    int32x4 b = x[t * 4 + 1];
    int32x4 c = x[t * 4 + 2];
    int32x4 d = x[t * 4 + 3];
    int32x4 o;
    o.x = (a.x & 255) | ((a.y & 255) << 8) | ((a.z & 255) << 16) | (a.w << 24);
    o.y = (b.x & 255) | ((b.y & 255) << 8) | ((b.z & 255) << 16) | (b.w << 24);
    o.z = (c.x & 255) | ((c.y & 255) << 8) | ((c.z & 255) << 16) | (c.w << 24);
    o.w = (d.x & 255) | ((d.y & 255) << 8) | ((d.z & 255) << 16) | (d.w << 24);
    xp[t] = o;
}

// ---------------------------------------------------------------------------
// Kernel 2: weight transform — int32 [K][N] -> int8 [N][K]
// ---------------------------------------------------------------------------
__global__ __launch_bounds__(256) void transform_w_kernel(const int* __restrict__ w,
                                                          unsigned char* __restrict__ wt,
                                                          int K, int N) {
    __shared__ unsigned char tileT[64][72];
    int tx = threadIdx.x & 15;
    int ty = threadIdx.x >> 4;
    int n0 = blockIdx.x * 64;
    int k0 = blockIdx.y * 64;
#pragma unroll
    for (int r = 0; r < 4; ++r) {
        int row = ty * 4 + r;  // k_local
        int32x4 v = *(const int32x4*)&w[(size_t)(k0 + row) * N + n0 + tx * 4];
        tileT[tx * 4 + 0][row] = (unsigned char)(v.x & 255);
        tileT[tx * 4 + 1][row] = (unsigned char)(v.y & 255);
        tileT[tx * 4 + 2][row] = (unsigned char)(v.z & 255);
        tileT[tx * 4 + 3][row] = (unsigned char)(v.w & 255);
    }
    __syncthreads();
#pragma unroll
    for (int r = 0; r < 4; ++r) {
        int row = ty * 4 + r;  // n_local
        uchar4 v = *(const uchar4*)&tileT[row][tx * 4];
        *(uchar4*)&wt[(size_t)(n0 + row) * K + k0 + tx * 4] = v;
    }
}

// ---------------------------------------------------------------------------
// Kernel 3: int8 GEMM — m201-style 4-phase/K-tile template at feasible
// geometry: 256x128 tile, 8 waves (4Mx2N, 64x64 out each), K-tile = 128B.
// Each phase: {ds_read next subtile | 1 GLL-pair stage | BARR | counted
// lgkm | 8 MFMA | BARR}. 3-deep 48KB ring (144KB); ONE VMW(6) per K-tile.
// 128B-row XOR swizzle (r11-verified 0-conflict fragment family).
// ---------------------------------------------------------------------------
__global__ __launch_bounds__(512, 2) void gemm_i8_4p(
    const char* __restrict__ A,   // [M][K] int8
    const char* __restrict__ Bt,  // [N][K] int8
    const int* __restrict__ bias,
    const int* __restrict__ shiftp,
    int* __restrict__ C,          // [M][N]
    int M, int N, int K) {
    __shared__ char smem[3 * BUFSZ];  // 144 KiB

    const int nbn = N / BN;  // 32
    const int nwg = gridDim.x;
    const int bid = blockIdx.x;
    const int cpx = nwg >> 3;  // nwg % 8 == 0 -> bijective XCD swizzle
    const int swz = (bid & 7) * cpx + (bid >> 3);
    const int m0 = (swz / nbn) * BM;
    const int n0 = (swz % nbn) * BN;

    const int t = threadIdx.x;
    const int lane = t & 63;
    const int wave = t >> 6;
    const int wr = wave >> 1;  // 0..3  (M quarter, 64 rows)
    const int wc = wave & 1;   // 0..1  (N half, 64 cols)

    // ---- staging geometry (pre-swizzled source, linear GLL dest; r11) ----
    // one GLL: 512 thr x 16B = 8KB = 64 rows x 128B.
    const int s_row = t >> 3;                               // 0..63
    const int s_col = (((t & 7) ^ ((t >> 3) & 7)) << 4);
    const char* a_src = A + (size_t)(m0 + s_row) * K + s_col;
    const char* b_src = Bt + (size_t)(n0 + s_row) * K + s_col;
    const size_t jstr = (size_t)64 * K;
    char* lds_st = smem + t * 16;

    // ---- fragment-read geometry (128B rows; r11-verified 0-conflict) ----
    const int lr = lane & 15;
    const int lc = (lane >> 4) << 4;   // 0,16,32,48
    const int xr = (lr & 7) << 4;
    const int rowA = (wr << 6) + lr;   // + mf*16 rows (mf*2048 bytes)
    const int rowB = (wc << 6) + lr;   // + nf*16 rows (nf*2048 bytes)
    const int a_s0 = rowA * 128 + (lc ^ xr);
    const int a_s1 = rowA * 128 + ((lc | 64) ^ xr);
    const int b_s0 = 32768 + rowB * 128 + (lc ^ xr);
    const int b_s1 = 32768 + rowB * 128 + ((lc | 64) ^ xr);

    int32x4 acc[4][4] = {};
    int32x4 afX[4], afY[4], bfX[2], bfY[2];

    const int nt = K / 128;  // 32 K-tiles

#define GLL(src, dst)                                                 \
    __builtin_amdgcn_global_load_lds(                                 \
        (const __attribute__((address_space(1))) void*)(src),        \
        (__attribute__((address_space(3))) void*)(dst), 16, 0, 0)

#define FENCE asm volatile("" ::: "memory")
#define BARR                           \
    do {                               \
        FENCE;                         \
        __builtin_amdgcn_s_barrier();  \
        FENCE;                         \
    } while (0)
#define SB0 __builtin_amdgcn_sched_barrier(0)
#define LGKM(n)                                                   \
    do {                                                          \
        asm volatile("s_waitcnt lgkmcnt(" #n ")" ::: "memory");   \
        SB0;                                                      \
    } while (0)
#define VMW(n)                                                  \
    do {                                                        \
        asm volatile("s_waitcnt vmcnt(" #n ")" ::: "memory");   \
        SB0;                                                    \
    } while (0)

    // 8 MFMA: 4 mf x 2 nf into acc[.][NC..NC+1]
#define MFMA8(AF, BF, NC)                                                        \
    do {                                                                         \
        __builtin_amdgcn_s_setprio(1);                                           \
        _Pragma("unroll") for (int mi = 0; mi < 4; ++mi)                         \
            _Pragma("unroll") for (int nj = 0; nj < 2; ++nj)                     \
                acc[mi][(NC) + nj] = __builtin_amdgcn_mfma_i32_16x16x64_i8(      \
                    AF[mi], BF[nj], acc[mi][(NC) + nj], 0, 0, 0);                \
        __builtin_amdgcn_s_setprio(0);                                           \
    } while (0)

    // stage all 6 chunks of K-tile TT into BUF (prologue only)
#define STAGE6(TT, BUF)                                                       \
    do {                                                                      \
        const size_t kc_ = (size_t)(TT) * 128;                                \
        _Pragma("unroll") for (int j = 0; j < 4; ++j)                         \
            GLL(a_src + kc_ + j * jstr, lds_st + (BUF) + j * 8192);           \
        _Pragma("unroll") for (int j = 0; j < 2; ++j)                         \
            GLL(b_src + kc_ + j * jstr, lds_st + (BUF) + 32768 + j * 8192);   \
    } while (0)

    // One K-tile TT: data in BA, tile TT+1 in BB, stage TT+2 -> BC (no WAR:
    // BC is never read this tile). Entry regs: afX=(BA,ks0,mf0-3),
    // bfX=(BA,ks0,nf0-1) — read in previous tile's P4, waited by P1's LGKM.
#define TILE(BA, BB, BC, TT, ST, WTAIL, RN)                                        \
    do {                                                                           \
        const size_t kc_ = (size_t)((TT) + 2) * 128;                               \
        /* ---- P1: read bfY(ks0,nf2-3); stage A01 ---- */                         \
        _Pragma("unroll") for (int i = 0; i < 2; ++i)                              \
            bfY[i] = *(const int32x4*)&smem[(BA) + b_s0 + (2 + i) * 2048];         \
        if (ST) {                                                                  \
            GLL(a_src + kc_, lds_st + (BC));                                       \
            GLL(a_src + kc_ + jstr, lds_st + (BC) + 8192);                         \
        }                                                                          \
        BARR; LGKM(2);                                                             \
        MFMA8(afX, bfX, 0); /* ks0, nf0-1 */                                       \
        BARR;                                                                      \
        /* ---- P2: read afY(ks1) + bfX(ks1,nf0-1); stage A23 ---- */              \
        _Pragma("unroll") for (int i = 0; i < 4; ++i)                              \
            afY[i] = *(const int32x4*)&smem[(BA) + a_s1 + i * 2048];               \
        _Pragma("unroll") for (int i = 0; i < 2; ++i)                              \
            bfX[i] = *(const int32x4*)&smem[(BA) + b_s1 + i * 2048];               \
        if (ST) {                                                                  \
            GLL(a_src + kc_ + 2 * jstr, lds_st + (BC) + 16384);                    \
            GLL(a_src + kc_ + 3 * jstr, lds_st + (BC) + 24576);                    \
        }                                                                          \
        BARR; LGKM(6);                                                             \
        MFMA8(afX, bfY, 2); /* ks0, nf2-3 */                                       \
        BARR;                                                                      \
        /* ---- P3: read bfY(ks1,nf2-3); stage B01; VMW ---- */                    \
        _Pragma("unroll") for (int i = 0; i < 2; ++i)                              \
            bfY[i] = *(const int32x4*)&smem[(BA) + b_s1 + (2 + i) * 2048];         \
        if (ST) {                                                                  \
            GLL(b_src + kc_, lds_st + (BC) + 32768);                               \
            GLL(b_src + kc_ + jstr, lds_st + (BC) + 40960);                        \
        }                                                                          \
        BARR; LGKM(2);                                                             \
        MFMA8(afY, bfX, 0); /* ks1, nf0-1 */                                       \
        WTAIL;  /* counted vmcnt: stage(TT+1) drained before P4 reads BB */        \
        BARR;                                                                      \
        /* ---- P4: read next tile's afX,bfX from BB ---- */                       \
        if (RN) {                                                                  \
            _Pragma("unroll") for (int i = 0; i < 4; ++i)                          \
                afX[i] = *(const int32x4*)&smem[(BB) + a_s0 + i * 2048];           \
            _Pragma("unroll") for (int i = 0; i < 2; ++i)                          \
                bfX[i] = *(const int32x4*)&smem[(BB) + b_s0 + i * 2048];           \
        }                                                                          \
        BARR;                                                                      \
        if (RN) { LGKM(6); } else { LGKM(0); }                                     \
        MFMA8(afY, bfY, 2); /* ks1, nf2-3 */                                       \
        BARR;                                                                      \
    } while (0)

    // ---- prologue: stage tiles 0 and 1 ----
    STAGE6(0, 0);
    STAGE6(1, BUFSZ);
    VMW(6);  // drain stage(0); stage(1) in flight
    BARR;
#pragma unroll
    for (int i = 0; i < 4; ++i) afX[i] = *(const int32x4*)&smem[a_s0 + i * 2048];
#pragma unroll
    for (int i = 0; i < 2; ++i) bfX[i] = *(const int32x4*)&smem[b_s0 + i * 2048];
    LGKM(0);

    // ---- main loop (3-way rotating ring) ----
    int ba = 0, bb = BUFSZ, bc = 2 * BUFSZ;
    for (int tt = 0; tt < nt - 2; ++tt) {
        TILE(ba, bb, bc, tt, 1, VMW(6), 1);
        int tmp = ba; ba = bb; bb = bc; bc = tmp;
    }
    TILE(ba, bb, bc, nt - 2, 0, VMW(0), 1);
    { int tmp = ba; ba = bb; bb = bc; bc = tmp; }
    TILE(ba, bb, bc, nt - 1, 0, (void)0, 0);

    // ---- epilogue: bias + shift, int32 store (16x16 C/D layout) ----
    const int s = *shiftp;
    const int crow = (lane >> 4) << 2;
    const int ccol = lane & 15;
    int bv[4];
#pragma unroll
    for (int nf = 0; nf < 4; ++nf) bv[nf] = bias[n0 + wc * 64 + nf * 16 + ccol];
#pragma unroll
    for (int mf = 0; mf < 4; ++mf) {
        const int grow0 = m0 + wr * 64 + mf * 16 + crow;
#pragma unroll
        for (int nf = 0; nf < 4; ++nf) {
            const int gcol = n0 + wc * 64 + nf * 16 + ccol;
#pragma unroll
            for (int r = 0; r < 4; ++r) {
                int y = acc[mf][nf][r] + bv[nf];
                y = (s > 0) ? (y >> s) : y;
                C[(size_t)(grow0 + r) * N + gcol] = y;
            }
        }
    }
#undef GLL
#undef FENCE
#undef BARR
#undef SB0
#undef LGKM
#undef VMW
#undef MFMA8
#undef STAGE6
#undef TILE
}

// ---------------------------------------------------------------------------
extern "C" void kernel_launch(void* const* d_in, const int* in_sizes, int n_in,
                              void* d_out, int out_size, void* d_ws, size_t ws_size,
                              hipStream_t stream) {
    const int* x = (const int*)d_in[0];
    const int* w = (const int*)d_in[1];   // int8 values stored as int32
    const int* bias = (const int*)d_in[2];
    const int* shiftp = (const int*)d_in[3];
    int* out = (int*)d_out;

    const int N = in_sizes[2];      // 4096
    const int K = in_sizes[1] / N;  // 4096
    const int M = in_sizes[0] / K;  // 8192

    char* xp = (char*)d_ws;
    unsigned char* wt = (unsigned char*)d_ws + (size_t)M * K;

    int nvec = (int)(((long long)M * K) / 16);
    pack_x_kernel<<<(nvec + 255) / 256, 256, 0, stream>>>((const int32x4*)x, (int32x4*)xp, nvec);

    dim3 tgrid(N / 64, K / 64);
    transform_w_kernel<<<tgrid, 256, 0, stream>>>(w, wt, K, N);

    int nwg = (M / BM) * (N / BN);  // 32*32 = 1024, %8==0
    gemm_i8_4p<<<nwg, 512, 0, stream>>>(xp, (const char*)wt, bias, shiftp, out, M, N, K);
}